// Round 4
// baseline (362.282 us; speedup 1.0000x reference)
//
#include <hip/hip_runtime.h>

// ---------------------------------------------------------------------------
// FP8Linear: out = (q8(x*sx) @ q8(W*sw)^T) / (sx*sw) + bias
// M=16384, K=2048, N=2048
// R6: GEMM K-loop -> 2-phase double-buffered pipeline with counted vmcnt
// (T3-minimal + T4): stage(t+1) issued BEFORE compute(t); s_waitcnt vmcnt(8)
// + raw s_barrier keeps next tile's 8 global_load_lds in flight across the
// barrier. LDS 2x32KB. Side kernels UNCHANGED (single-variable round; they
// become visible in top-5 iff they are the real bottleneck once gemm drops).
// ---------------------------------------------------------------------------

typedef __attribute__((ext_vector_type(4))) float floatx4;
typedef __attribute__((ext_vector_type(4))) int intx4;
typedef __attribute__((ext_vector_type(8))) int intx8;

#define FP8_MAX_F 448.0f
#define SGRID 2048

__device__ __forceinline__ void async_load16(const void* g, void* l) {
    __builtin_amdgcn_global_load_lds(
        (const __attribute__((address_space(1))) unsigned int*)g,
        (__attribute__((address_space(3))) unsigned int*)l,
        16, 0, 0);
}

__device__ __forceinline__ float scale_from_amax_f(float a) {
    // must be the exact fp32 op sequence everywhere it is recomputed
    return FP8_MAX_F / (a + 1e-12f) * 0.9f;
}
__device__ __forceinline__ float scale_from_amax(unsigned int bits) {
    return scale_from_amax_f(__uint_as_float(bits));
}

__device__ __forceinline__ float amax4(float4 v) {
    return fmaxf(fmaxf(fabsf(v.x), fabsf(v.y)), fmaxf(fabsf(v.z), fabsf(v.w)));
}

// --- pass 1: per-block partial amax over x and w. 8-deep batched loads.
__global__ __launch_bounds__(256) void amax_partial(
    const float* __restrict__ x, long xn4,
    const float* __restrict__ w, long wn4,
    float* __restrict__ partials) {  // [2][SGRID] in ws
    const float4* xv = (const float4*)x;
    const float4* wv = (const float4*)w;
    const long tid = (long)blockIdx.x * 256 + threadIdx.x;
    const long st = (long)SGRID * 256;

    float mx = 0.0f, mw = 0.0f;
    long j = tid;
    for (; j + 7 * st < xn4; j += 8 * st) {
        float4 a0 = xv[j];
        float4 a1 = xv[j + st];
        float4 a2 = xv[j + 2 * st];
        float4 a3 = xv[j + 3 * st];
        float4 a4 = xv[j + 4 * st];
        float4 a5 = xv[j + 5 * st];
        float4 a6 = xv[j + 6 * st];
        float4 a7 = xv[j + 7 * st];
        float m01 = fmaxf(amax4(a0), amax4(a1));
        float m23 = fmaxf(amax4(a2), amax4(a3));
        float m45 = fmaxf(amax4(a4), amax4(a5));
        float m67 = fmaxf(amax4(a6), amax4(a7));
        mx = fmaxf(mx, fmaxf(fmaxf(m01, m23), fmaxf(m45, m67)));
    }
    for (; j < xn4; j += st) mx = fmaxf(mx, amax4(xv[j]));

    j = tid;
    for (; j + st < wn4; j += 2 * st) {
        float4 b0 = wv[j];
        float4 b1 = wv[j + st];
        mw = fmaxf(mw, fmaxf(amax4(b0), amax4(b1)));
    }
    for (; j < wn4; j += st) mw = fmaxf(mw, amax4(wv[j]));

    #pragma unroll
    for (int off = 32; off > 0; off >>= 1) {
        mx = fmaxf(mx, __shfl_down(mx, off));
        mw = fmaxf(mw, __shfl_down(mw, off));
    }
    __shared__ float red[2][4];
    const int lane = threadIdx.x & 63, wid = threadIdx.x >> 6;
    if (lane == 0) { red[0][wid] = mx; red[1][wid] = mw; }
    __syncthreads();
    if (threadIdx.x == 0) {
        partials[blockIdx.x] =
            fmaxf(fmaxf(red[0][0], red[0][1]), fmaxf(red[0][2], red[0][3]));
        partials[SGRID + blockIdx.x] =
            fmaxf(fmaxf(red[1][0], red[1][1]), fmaxf(red[1][2], red[1][3]));
    }
}

// --- pass 2: redundant partials reduce (every block, deterministic) ->
// write amax bits (block 0) -> quantize x and w.
__global__ __launch_bounds__(256) void quant_both(
    const float* __restrict__ x, long xn4,
    const float* __restrict__ w, long wn4,
    const float* __restrict__ partials,
    unsigned int* __restrict__ amax,    // 2 u32 for gemm epilogue
    unsigned int* __restrict__ xq,
    unsigned int* __restrict__ wq) {
    float mx = 0.0f, mw = 0.0f;
    for (int p = threadIdx.x; p < SGRID; p += 256) {
        mx = fmaxf(mx, partials[p]);
        mw = fmaxf(mw, partials[SGRID + p]);
    }
    #pragma unroll
    for (int off = 32; off > 0; off >>= 1) {
        mx = fmaxf(mx, __shfl_down(mx, off));
        mw = fmaxf(mw, __shfl_down(mw, off));
    }
    __shared__ float red[2][4];
    const int lane = threadIdx.x & 63, wid = threadIdx.x >> 6;
    if (lane == 0) { red[0][wid] = mx; red[1][wid] = mw; }
    __syncthreads();
    mx = fmaxf(fmaxf(red[0][0], red[0][1]), fmaxf(red[0][2], red[0][3]));
    mw = fmaxf(fmaxf(red[1][0], red[1][1]), fmaxf(red[1][2], red[1][3]));
    if (blockIdx.x == 0 && threadIdx.x == 0) {
        amax[0] = __float_as_uint(mx);
        amax[1] = __float_as_uint(mw);
    }

    const float sx = scale_from_amax_f(mx);
    const float sw = scale_from_amax_f(mw);
    const float4* xv = (const float4*)x;
    const float4* wv = (const float4*)w;
    const long tid = (long)blockIdx.x * 256 + threadIdx.x;
    const long st = (long)SGRID * 256;

    long j = tid;
    for (; j + 3 * st < xn4; j += 4 * st) {
        float4 v0 = xv[j];
        float4 v1 = xv[j + st];
        float4 v2 = xv[j + 2 * st];
        float4 v3 = xv[j + 3 * st];
        unsigned int q[4];
        float4 vv[4] = {v0, v1, v2, v3};
        #pragma unroll
        for (int u = 0; u < 4; u++) {
            float a0 = fminf(fmaxf(vv[u].x * sx, -FP8_MAX_F), FP8_MAX_F);
            float a1 = fminf(fmaxf(vv[u].y * sx, -FP8_MAX_F), FP8_MAX_F);
            float a2 = fminf(fmaxf(vv[u].z * sx, -FP8_MAX_F), FP8_MAX_F);
            float a3 = fminf(fmaxf(vv[u].w * sx, -FP8_MAX_F), FP8_MAX_F);
            int p = __builtin_amdgcn_cvt_pk_fp8_f32(a0, a1, 0, false);
            p = __builtin_amdgcn_cvt_pk_fp8_f32(a2, a3, p, true);
            q[u] = (unsigned int)p;
        }
        xq[j] = q[0];
        xq[j + st] = q[1];
        xq[j + 2 * st] = q[2];
        xq[j + 3 * st] = q[3];
    }
    for (; j < xn4; j += st) {
        float4 v = xv[j];
        float a0 = fminf(fmaxf(v.x * sx, -FP8_MAX_F), FP8_MAX_F);
        float a1 = fminf(fmaxf(v.y * sx, -FP8_MAX_F), FP8_MAX_F);
        float a2 = fminf(fmaxf(v.z * sx, -FP8_MAX_F), FP8_MAX_F);
        float a3 = fminf(fmaxf(v.w * sx, -FP8_MAX_F), FP8_MAX_F);
        int p = __builtin_amdgcn_cvt_pk_fp8_f32(a0, a1, 0, false);
        p = __builtin_amdgcn_cvt_pk_fp8_f32(a2, a3, p, true);
        xq[j] = (unsigned int)p;
    }

    j = tid;
    for (; j + st < wn4; j += 2 * st) {
        float4 v0 = wv[j];
        float4 v1 = wv[j + st];
        unsigned int q[2];
        float4 vv[2] = {v0, v1};
        #pragma unroll
        for (int u = 0; u < 2; u++) {
            float a0 = fminf(fmaxf(vv[u].x * sw, -FP8_MAX_F), FP8_MAX_F);
            float a1 = fminf(fmaxf(vv[u].y * sw, -FP8_MAX_F), FP8_MAX_F);
            float a2 = fminf(fmaxf(vv[u].z * sw, -FP8_MAX_F), FP8_MAX_F);
            float a3 = fminf(fmaxf(vv[u].w * sw, -FP8_MAX_F), FP8_MAX_F);
            int p = __builtin_amdgcn_cvt_pk_fp8_f32(a0, a1, 0, false);
            p = __builtin_amdgcn_cvt_pk_fp8_f32(a2, a3, p, true);
            q[u] = (unsigned int)p;
        }
        wq[j] = q[0];
        wq[j + st] = q[1];
    }
    for (; j < wn4; j += st) {
        float4 v = wv[j];
        float a0 = fminf(fmaxf(v.x * sw, -FP8_MAX_F), FP8_MAX_F);
        float a1 = fminf(fmaxf(v.y * sw, -FP8_MAX_F), FP8_MAX_F);
        float a2 = fminf(fmaxf(v.z * sw, -FP8_MAX_F), FP8_MAX_F);
        float a3 = fminf(fmaxf(v.w * sw, -FP8_MAX_F), FP8_MAX_F);
        int p = __builtin_amdgcn_cvt_pk_fp8_f32(a0, a1, 0, false);
        p = __builtin_amdgcn_cvt_pk_fp8_f32(a2, a3, p, true);
        wq[j] = (unsigned int)p;
    }
}

// --- GEMM: C[m,n] = sum_k A8[m,k]*W8[n,k]; epilogue C = acc*rcp + bias[n]
// 128x128 tile, BK=128 bytes, 4 waves x 4x4 tiles of 16x16x128 scaled-fp8 MFMA.
// Double-buffered LDS, XOR-swizzled at 16B granularity: LDS[r][b]=G[r][b^(r&7)].
// Pipeline per K-step: STAGE(next buf) -> s_waitcnt vmcnt(8) -> s_barrier ->
// compute(cur) -> lgkmcnt(0) -> s_barrier. Next tile's loads stay in flight
// across the barrier (counted vmcnt, never drained to 0 mid-loop).
#define BM 128
#define BN 128
#define BKB 128

__global__ __launch_bounds__(256, 2) void gemm_fp8mx(
    const unsigned char* __restrict__ A,  // [M,K] fp8
    const unsigned char* __restrict__ B,  // [N,K] fp8
    const float* __restrict__ bias,       // [N]
    const unsigned int* __restrict__ amax,
    float* __restrict__ C,                // [M,N] fp32
    int M, int N, int K) {
    __shared__ __align__(16) unsigned char As[2][BM * BKB];  // 2x16 KB
    __shared__ __align__(16) unsigned char Bs[2][BN * BKB];  // 2x16 KB

    const int t = threadIdx.x;
    const int lane = t & 63;
    const int w = t >> 6;

    // XCD-aware bijective swizzle: XCD k (flat%8==k) computes 256 consecutive
    // tiles = 16 full A-panel rows x all 16 B columns -> B L2-resident per XCD.
    int flat = blockIdx.y * gridDim.x + blockIdx.x;
    const int nwg = gridDim.x * gridDim.y;
    if ((nwg & 7) == 0) flat = (flat & 7) * (nwg >> 3) + (flat >> 3);
    const int bm = (flat / gridDim.x) * BM;
    const int bn = (flat % gridDim.x) * BN;

    const int wm = (w >> 1) * 64;
    const int wn = (w & 1) * 64;

    floatx4 acc[4][4] = {};

    // staging: thread t -> LDS linear slot t*16 == (row = t>>3, blk = t&7);
    // load the XOR-swizzled global 16B block so LDS[r][b] = G[r][b^(r&7)]
    const int srow = t >> 3;                       // 0..31
    const int gcol = ((t & 7) ^ (srow & 7)) * 16;  // swizzled 16B block
    const unsigned char* gA = A + (long)(bm + srow) * K + gcol;
    const unsigned char* gB = B + (long)(bn + srow) * K + gcol;

    // fragment addressing: 16x16x128 f8f6f4 A/B: lane holds
    // elem (l&15, (l>>4)*32 + j), j=0..31 -> two swizzled 16B reads
    const int fr = lane & 15;
    const int sw = fr & 7;
    const int b0 = (lane >> 4) * 2;
    const int off0 = (b0 ^ sw) * 16;
    const int off1 = ((b0 + 1) ^ sw) * 16;
    const int rowA = (wm + fr) * BKB;
    const int rowB = (wn + fr) * BKB;

    const int nt = K / BKB;  // 16

    // prologue: stage tile 0 into buffer 0 (8 async loads, stay in flight)
    #pragma unroll
    for (int c = 0; c < 4; c++) {
        async_load16(gA + (long)c * 32 * K, &As[0][t * 16 + c * 4096]);
        async_load16(gB + (long)c * 32 * K, &Bs[0][t * 16 + c * 4096]);
    }

    for (int kt = 0; kt < nt; ++kt) {
        const int cur = kt & 1;
        if (kt + 1 < nt) {
            // stage next tile into the other buffer (8 more in flight)
            const long ko = (long)(kt + 1) * BKB;
            #pragma unroll
            for (int c = 0; c < 4; c++) {
                async_load16(gA + (long)c * 32 * K + ko,
                             &As[cur ^ 1][t * 16 + c * 4096]);
                async_load16(gB + (long)c * 32 * K + ko,
                             &Bs[cur ^ 1][t * 16 + c * 4096]);
            }
            // wait only for cur's 8 loads (in-order completion); next's 8
            // remain in flight across the barrier
            asm volatile("s_waitcnt vmcnt(8)" ::: "memory");
        } else {
            asm volatile("s_waitcnt vmcnt(0)" ::: "memory");
        }
        __builtin_amdgcn_s_barrier();
        __builtin_amdgcn_sched_barrier(0);

        const unsigned char* Ab = As[cur];
        const unsigned char* Bb = Bs[cur];
        intx8 bfrag[4];
        #pragma unroll
        for (int j = 0; j < 4; j++) {
            intx4 lo = *(const intx4*)(Bb + rowB + j * 2048 + off0);
            intx4 hi = *(const intx4*)(Bb + rowB + j * 2048 + off1);
            bfrag[j] = (intx8){lo.x, lo.y, lo.z, lo.w, hi.x, hi.y, hi.z, hi.w};
        }
        #pragma unroll
        for (int i = 0; i < 4; i++) {
            intx4 lo = *(const intx4*)(Ab + rowA + i * 2048 + off0);
            intx4 hi = *(const intx4*)(Ab + rowA + i * 2048 + off1);
            intx8 afrag = (intx8){lo.x, lo.y, lo.z, lo.w, hi.x, hi.y, hi.z, hi.w};
            #pragma unroll
            for (int j = 0; j < 4; j++)
                acc[i][j] = __builtin_amdgcn_mfma_scale_f32_16x16x128_f8f6f4(
                    afrag, bfrag[j], acc[i][j],
                    /*cbsz=fp8*/ 0, /*blgp=fp8*/ 0,
                    0, 0x7f7f7f7f, 0, 0x7f7f7f7f);  // unit e8m0 scales
        }

        // all ds_reads of cur drained before any wave re-stages this buffer
        asm volatile("s_waitcnt lgkmcnt(0)" ::: "memory");
        __builtin_amdgcn_sched_barrier(0);
        __builtin_amdgcn_s_barrier();
    }

    // epilogue: C/D layout col = lane&15, row = (lane>>4)*4 + reg (16x16 shapes)
    const float is = scale_from_amax(amax[0]);
    const float ws = scale_from_amax(amax[1]);
    const float rcp = 1.0f / (is * ws);
    const int crow = bm + wm + (lane >> 4) * 4;
    const int ccol = bn + wn + fr;
    #pragma unroll
    for (int j = 0; j < 4; j++) {
        const int col = ccol + j * 16;
        const float bv = bias[col];
        #pragma unroll
        for (int i = 0; i < 4; i++) {
            const int row0 = crow + i * 16;
            #pragma unroll
            for (int r = 0; r < 4; r++)
                __builtin_nontemporal_store(acc[i][j][r] * rcp + bv,
                                            &C[(long)(row0 + r) * N + col]);
        }
    }
}

extern "C" void kernel_launch(void* const* d_in, const int* in_sizes, int n_in,
                              void* d_out, int out_size, void* d_ws, size_t ws_size,
                              hipStream_t stream) {
    const float* x = (const float*)d_in[0];    // [B,S,K] fp32
    const float* wt = (const float*)d_in[1];   // [N,K] fp32
    const float* bias = (const float*)d_in[2]; // [N] fp32
    float* out = (float*)d_out;                // [B*S, N] fp32

    const int xn = in_sizes[0];  // M*K
    const int wn = in_sizes[1];  // N*K
    const int N = in_sizes[2];
    const int K = wn / N;
    const int M = xn / K;

    unsigned char* wsb = (unsigned char*)d_ws;
    unsigned int* amax = (unsigned int*)wsb;            // 2 u32
    float* partials = (float*)(wsb + 64);               // 2*SGRID floats
    unsigned char* xq = wsb + 64 + 2 * SGRID * 4;       // M*K bytes
    unsigned char* wq = xq + (size_t)xn;                // N*K bytes

    long xn4 = (long)xn / 4, wn4 = (long)wn / 4;
    amax_partial<<<SGRID, 256, 0, stream>>>(x, xn4, wt, wn4, partials);
    quant_both<<<SGRID, 256, 0, stream>>>(x, xn4, wt, wn4, partials, amax,
                                          (unsigned int*)xq, (unsigned int*)wq);
    dim3 grid(N / BN, M / BM);
    gemm_fp8mx<<<grid, 256, 0, stream>>>(xq, wq, bias, amax, out, M, N, K);
}

// Round 6
// 357.544 us; speedup vs baseline: 1.0133x; 1.0133x over previous
//
#include <hip/hip_runtime.h>

// ---------------------------------------------------------------------------
// FP8Linear: out = (q8(x*sx) @ q8(W*sw)^T) / (sx*sw) + bias
// M=16384, K=2048, N=2048
// R8 (= R7 fixed): compile error was the local pointer-array initialized from
// extern __shared__ (hipcc folds the addrspacecast into a static initializer
// and rejects it). Buffers now addressed as smem + cur*2*TILE_BYTES inline.
// GEMM: 256x256 tile, 512 threads (8 waves, 2Mx4N), BK=128B, double-buffered
// 128KB dynamic LDS (1 block/CU: ILP replaces TLP). Tile t+1's 8
// global_load_lds issued at top of tile t -> vmcnt(8) covered by a full
// K-tile of compute. 4 phases/tile: {2 A-frag ds_read -> lgkmcnt(0) ->
// setprio(1) 8 MFMA}. 2 barriers per K-tile. Side kernels unchanged.
// ---------------------------------------------------------------------------

typedef __attribute__((ext_vector_type(4))) float floatx4;
typedef __attribute__((ext_vector_type(4))) int intx4;
typedef __attribute__((ext_vector_type(8))) int intx8;

#define FP8_MAX_F 448.0f
#define SGRID 2048

__device__ __forceinline__ void async_load16(const void* g, void* l) {
    __builtin_amdgcn_global_load_lds(
        (const __attribute__((address_space(1))) unsigned int*)g,
        (__attribute__((address_space(3))) unsigned int*)l,
        16, 0, 0);
}

__device__ __forceinline__ float scale_from_amax_f(float a) {
    // must be the exact fp32 op sequence everywhere it is recomputed
    return FP8_MAX_F / (a + 1e-12f) * 0.9f;
}
__device__ __forceinline__ float scale_from_amax(unsigned int bits) {
    return scale_from_amax_f(__uint_as_float(bits));
}

__device__ __forceinline__ float amax4(float4 v) {
    return fmaxf(fmaxf(fabsf(v.x), fabsf(v.y)), fmaxf(fabsf(v.z), fabsf(v.w)));
}

// --- pass 1: per-block partial amax over x and w. 8-deep batched loads.
__global__ __launch_bounds__(256) void amax_partial(
    const float* __restrict__ x, long xn4,
    const float* __restrict__ w, long wn4,
    float* __restrict__ partials) {  // [2][SGRID] in ws
    const float4* xv = (const float4*)x;
    const float4* wv = (const float4*)w;
    const long tid = (long)blockIdx.x * 256 + threadIdx.x;
    const long st = (long)SGRID * 256;

    float mx = 0.0f, mw = 0.0f;
    long j = tid;
    for (; j + 7 * st < xn4; j += 8 * st) {
        float4 a0 = xv[j];
        float4 a1 = xv[j + st];
        float4 a2 = xv[j + 2 * st];
        float4 a3 = xv[j + 3 * st];
        float4 a4 = xv[j + 4 * st];
        float4 a5 = xv[j + 5 * st];
        float4 a6 = xv[j + 6 * st];
        float4 a7 = xv[j + 7 * st];
        float m01 = fmaxf(amax4(a0), amax4(a1));
        float m23 = fmaxf(amax4(a2), amax4(a3));
        float m45 = fmaxf(amax4(a4), amax4(a5));
        float m67 = fmaxf(amax4(a6), amax4(a7));
        mx = fmaxf(mx, fmaxf(fmaxf(m01, m23), fmaxf(m45, m67)));
    }
    for (; j < xn4; j += st) mx = fmaxf(mx, amax4(xv[j]));

    j = tid;
    for (; j + st < wn4; j += 2 * st) {
        float4 b0 = wv[j];
        float4 b1 = wv[j + st];
        mw = fmaxf(mw, fmaxf(amax4(b0), amax4(b1)));
    }
    for (; j < wn4; j += st) mw = fmaxf(mw, amax4(wv[j]));

    #pragma unroll
    for (int off = 32; off > 0; off >>= 1) {
        mx = fmaxf(mx, __shfl_down(mx, off));
        mw = fmaxf(mw, __shfl_down(mw, off));
    }
    __shared__ float red[2][4];
    const int lane = threadIdx.x & 63, wid = threadIdx.x >> 6;
    if (lane == 0) { red[0][wid] = mx; red[1][wid] = mw; }
    __syncthreads();
    if (threadIdx.x == 0) {
        partials[blockIdx.x] =
            fmaxf(fmaxf(red[0][0], red[0][1]), fmaxf(red[0][2], red[0][3]));
        partials[SGRID + blockIdx.x] =
            fmaxf(fmaxf(red[1][0], red[1][1]), fmaxf(red[1][2], red[1][3]));
    }
}

// --- pass 2: redundant partials reduce (every block, deterministic) ->
// write amax bits (block 0) -> quantize x and w.
__global__ __launch_bounds__(256) void quant_both(
    const float* __restrict__ x, long xn4,
    const float* __restrict__ w, long wn4,
    const float* __restrict__ partials,
    unsigned int* __restrict__ amax,    // 2 u32 for gemm epilogue
    unsigned int* __restrict__ xq,
    unsigned int* __restrict__ wq) {
    float mx = 0.0f, mw = 0.0f;
    for (int p = threadIdx.x; p < SGRID; p += 256) {
        mx = fmaxf(mx, partials[p]);
        mw = fmaxf(mw, partials[SGRID + p]);
    }
    #pragma unroll
    for (int off = 32; off > 0; off >>= 1) {
        mx = fmaxf(mx, __shfl_down(mx, off));
        mw = fmaxf(mw, __shfl_down(mw, off));
    }
    __shared__ float red[2][4];
    const int lane = threadIdx.x & 63, wid = threadIdx.x >> 6;
    if (lane == 0) { red[0][wid] = mx; red[1][wid] = mw; }
    __syncthreads();
    mx = fmaxf(fmaxf(red[0][0], red[0][1]), fmaxf(red[0][2], red[0][3]));
    mw = fmaxf(fmaxf(red[1][0], red[1][1]), fmaxf(red[1][2], red[1][3]));
    if (blockIdx.x == 0 && threadIdx.x == 0) {
        amax[0] = __float_as_uint(mx);
        amax[1] = __float_as_uint(mw);
    }

    const float sx = scale_from_amax_f(mx);
    const float sw = scale_from_amax_f(mw);
    const float4* xv = (const float4*)x;
    const float4* wv = (const float4*)w;
    const long tid = (long)blockIdx.x * 256 + threadIdx.x;
    const long st = (long)SGRID * 256;

    long j = tid;
    for (; j + 3 * st < xn4; j += 4 * st) {
        float4 v0 = xv[j];
        float4 v1 = xv[j + st];
        float4 v2 = xv[j + 2 * st];
        float4 v3 = xv[j + 3 * st];
        unsigned int q[4];
        float4 vv[4] = {v0, v1, v2, v3};
        #pragma unroll
        for (int u = 0; u < 4; u++) {
            float a0 = fminf(fmaxf(vv[u].x * sx, -FP8_MAX_F), FP8_MAX_F);
            float a1 = fminf(fmaxf(vv[u].y * sx, -FP8_MAX_F), FP8_MAX_F);
            float a2 = fminf(fmaxf(vv[u].z * sx, -FP8_MAX_F), FP8_MAX_F);
            float a3 = fminf(fmaxf(vv[u].w * sx, -FP8_MAX_F), FP8_MAX_F);
            int p = __builtin_amdgcn_cvt_pk_fp8_f32(a0, a1, 0, false);
            p = __builtin_amdgcn_cvt_pk_fp8_f32(a2, a3, p, true);
            q[u] = (unsigned int)p;
        }
        xq[j] = q[0];
        xq[j + st] = q[1];
        xq[j + 2 * st] = q[2];
        xq[j + 3 * st] = q[3];
    }
    for (; j < xn4; j += st) {
        float4 v = xv[j];
        float a0 = fminf(fmaxf(v.x * sx, -FP8_MAX_F), FP8_MAX_F);
        float a1 = fminf(fmaxf(v.y * sx, -FP8_MAX_F), FP8_MAX_F);
        float a2 = fminf(fmaxf(v.z * sx, -FP8_MAX_F), FP8_MAX_F);
        float a3 = fminf(fmaxf(v.w * sx, -FP8_MAX_F), FP8_MAX_F);
        int p = __builtin_amdgcn_cvt_pk_fp8_f32(a0, a1, 0, false);
        p = __builtin_amdgcn_cvt_pk_fp8_f32(a2, a3, p, true);
        xq[j] = (unsigned int)p;
    }

    j = tid;
    for (; j + st < wn4; j += 2 * st) {
        float4 v0 = wv[j];
        float4 v1 = wv[j + st];
        unsigned int q[2];
        float4 vv[2] = {v0, v1};
        #pragma unroll
        for (int u = 0; u < 2; u++) {
            float a0 = fminf(fmaxf(vv[u].x * sw, -FP8_MAX_F), FP8_MAX_F);
            float a1 = fminf(fmaxf(vv[u].y * sw, -FP8_MAX_F), FP8_MAX_F);
            float a2 = fminf(fmaxf(vv[u].z * sw, -FP8_MAX_F), FP8_MAX_F);
            float a3 = fminf(fmaxf(vv[u].w * sw, -FP8_MAX_F), FP8_MAX_F);
            int p = __builtin_amdgcn_cvt_pk_fp8_f32(a0, a1, 0, false);
            p = __builtin_amdgcn_cvt_pk_fp8_f32(a2, a3, p, true);
            q[u] = (unsigned int)p;
        }
        wq[j] = q[0];
        wq[j + st] = q[1];
    }
    for (; j < wn4; j += st) {
        float4 v = wv[j];
        float a0 = fminf(fmaxf(v.x * sw, -FP8_MAX_F), FP8_MAX_F);
        float a1 = fminf(fmaxf(v.y * sw, -FP8_MAX_F), FP8_MAX_F);
        float a2 = fminf(fmaxf(v.z * sw, -FP8_MAX_F), FP8_MAX_F);
        float a3 = fminf(fmaxf(v.w * sw, -FP8_MAX_F), FP8_MAX_F);
        int p = __builtin_amdgcn_cvt_pk_fp8_f32(a0, a1, 0, false);
        p = __builtin_amdgcn_cvt_pk_fp8_f32(a2, a3, p, true);
        wq[j] = (unsigned int)p;
    }
}

// --- GEMM: C[m,n] = sum_k A8[m,k]*W8[n,k]; epilogue C = acc*rcp + bias[n]
// 256x256 tile, BK=128B, 512 threads = 8 waves (2Mx4N), wave tile 128x64.
// Double-buffered dynamic LDS 128KB, 16B-granular XOR swizzle:
// LDS[r][b] = G[r][b ^ (r&7)]. Buffer layout (byte offsets from smem):
//   buf0: A @ 0,      B @ 32K
//   buf1: A @ 64K,    B @ 96K       -> buffer base = cur * 64K
#define BM 256
#define BN 256
#define BKB 128
#define TILE_BYTES (BM * BKB)  // 32KB per operand per buffer

__global__ __launch_bounds__(512, 2) void gemm_fp8mx(
    const unsigned char* __restrict__ A,  // [M,K] fp8
    const unsigned char* __restrict__ B,  // [N,K] fp8
    const float* __restrict__ bias,       // [N]
    const unsigned int* __restrict__ amax,
    float* __restrict__ C,                // [M,N] fp32
    int M, int N, int K) {
    extern __shared__ unsigned char smem[];  // 128KB dynamic

    const int t = threadIdx.x;
    const int lane = t & 63;
    const int w = t >> 6;    // 0..7
    const int wr = w >> 2;   // 0..1  (M half)
    const int wc = w & 3;    // 0..3  (N quarter)

    // XCD-aware bijective swizzle (nwg=512, %8==0): XCD k gets 64 consecutive
    // tiles = 8 full A-panel rows x all 8 B columns -> A chunk + B (4MB)
    // mostly L2-resident per XCD.
    int flat = blockIdx.y * gridDim.x + blockIdx.x;
    const int nwg = gridDim.x * gridDim.y;
    if ((nwg & 7) == 0) flat = (flat & 7) * (nwg >> 3) + (flat >> 3);
    const int bm = (flat / gridDim.x) * BM;
    const int bn = (flat % gridDim.x) * BN;

    floatx4 acc[8][4] = {};

    // staging: thread t -> LDS linear slot t*16 + c*8192 == (row = t>>3 + c*64,
    // blk = t&7); global col XOR-swizzled so LDS[r][b] = G[r][b^(r&7)].
    // (row&7) == ((t>>3)&7) since c*64 is a multiple of 8.
    const int srow = t >> 3;                       // 0..63
    const int gcol = ((t & 7) ^ (srow & 7)) * 16;  // swizzled 16B block
    const unsigned char* gA = A + (long)(bm + srow) * K + gcol;
    const unsigned char* gB = B + (long)(bn + srow) * K + gcol;

    // fragment addressing: 16x16x128 f8f6f4: lane holds elem
    // (l&15, (l>>4)*32 + j), j=0..31 -> two swizzled 16B reads
    const int fr = lane & 15;
    const int sw = fr & 7;
    const int b0 = (lane >> 4) * 2;
    const int off0 = (b0 ^ sw) * 16;
    const int off1 = ((b0 + 1) ^ sw) * 16;
    const int rowA = (wr * 128 + fr) * BKB;  // + i*2048, i=0..7
    const int rowB = (wc * 64 + fr) * BKB;   // + j*2048, j=0..3

    const int nt = K / BKB;  // 16

    // prologue: stage tile 0 into buffer 0 (8 async loads)
    #pragma unroll
    for (int c = 0; c < 4; c++) {
        async_load16(gA + (long)c * 64 * K, smem + t * 16 + c * 8192);
        async_load16(gB + (long)c * 64 * K,
                     smem + TILE_BYTES + t * 16 + c * 8192);
    }

    for (int kt = 0; kt < nt; ++kt) {
        const int cur = kt & 1;
        const unsigned char* Ab = smem + cur * 2 * TILE_BYTES;
        const unsigned char* Bb = Ab + TILE_BYTES;

        // issue tile kt+1 into the other buffer (freed by kt-1's trailing
        // barrier), then wait for tile kt's 8 loads — issued a full K-tile of
        // compute ago, so the vmcnt(8) is already satisfied in steady state.
        if (kt + 1 < nt) {
            unsigned char* An = smem + (cur ^ 1) * 2 * TILE_BYTES;
            unsigned char* Bn = An + TILE_BYTES;
            const long ko = (long)(kt + 1) * BKB;
            #pragma unroll
            for (int c = 0; c < 4; c++) {
                async_load16(gA + (long)c * 64 * K + ko, An + t * 16 + c * 8192);
                async_load16(gB + (long)c * 64 * K + ko, Bn + t * 16 + c * 8192);
            }
            asm volatile("s_waitcnt vmcnt(8)" ::: "memory");
        } else {
            asm volatile("s_waitcnt vmcnt(0)" ::: "memory");
        }
        __builtin_amdgcn_sched_barrier(0);
        __builtin_amdgcn_s_barrier();  // tile kt staged & visible to all waves

        // B fragments once per K-tile (8 ds_read_b128)
        intx8 bfrag[4];
        #pragma unroll
        for (int j = 0; j < 4; j++) {
            intx4 lo = *(const intx4*)(Bb + rowB + j * 2048 + off0);
            intx4 hi = *(const intx4*)(Bb + rowB + j * 2048 + off1);
            bfrag[j] = (intx8){lo.x, lo.y, lo.z, lo.w, hi.x, hi.y, hi.z, hi.w};
        }
        // 4 phases x {2 A-rows ds_read -> drain -> 8 MFMA under setprio}.
        // Phases of the same tile have no cross-wave hazard -> no barriers.
        #pragma unroll
        for (int ph = 0; ph < 4; ph++) {
            intx8 af0, af1;
            {
                intx4 lo = *(const intx4*)(Ab + rowA + (2 * ph) * 2048 + off0);
                intx4 hi = *(const intx4*)(Ab + rowA + (2 * ph) * 2048 + off1);
                af0 = (intx8){lo.x, lo.y, lo.z, lo.w, hi.x, hi.y, hi.z, hi.w};
            }
            {
                intx4 lo = *(const intx4*)(Ab + rowA + (2 * ph + 1) * 2048 + off0);
                intx4 hi = *(const intx4*)(Ab + rowA + (2 * ph + 1) * 2048 + off1);
                af1 = (intx8){lo.x, lo.y, lo.z, lo.w, hi.x, hi.y, hi.z, hi.w};
            }
            asm volatile("s_waitcnt lgkmcnt(0)" ::: "memory");
            __builtin_amdgcn_sched_barrier(0);
            __builtin_amdgcn_s_setprio(1);
            #pragma unroll
            for (int j = 0; j < 4; j++)
                acc[2 * ph][j] = __builtin_amdgcn_mfma_scale_f32_16x16x128_f8f6f4(
                    af0, bfrag[j], acc[2 * ph][j], 0, 0, 0, 0x7f7f7f7f, 0,
                    0x7f7f7f7f);
            #pragma unroll
            for (int j = 0; j < 4; j++)
                acc[2 * ph + 1][j] =
                    __builtin_amdgcn_mfma_scale_f32_16x16x128_f8f6f4(
                        af1, bfrag[j], acc[2 * ph + 1][j], 0, 0, 0, 0x7f7f7f7f,
                        0, 0x7f7f7f7f);
            __builtin_amdgcn_s_setprio(0);
            __builtin_amdgcn_sched_barrier(0);
        }

        // all waves done reading buf[cur] before anyone re-stages it
        asm volatile("s_waitcnt lgkmcnt(0)" ::: "memory");
        __builtin_amdgcn_sched_barrier(0);
        __builtin_amdgcn_s_barrier();
    }

    // epilogue: C/D layout col = lane&15, row = (lane>>4)*4 + reg (16x16)
    const float is = scale_from_amax(amax[0]);
    const float ws = scale_from_amax(amax[1]);
    const float rcp = 1.0f / (is * ws);
    const int crow = bm + wr * 128 + (lane >> 4) * 4;
    const int ccol = bn + wc * 64 + fr;
    #pragma unroll
    for (int j = 0; j < 4; j++) {
        const int col = ccol + j * 16;
        const float bv = bias[col];
        #pragma unroll
        for (int i = 0; i < 8; i++) {
            const int row0 = crow + i * 16;
            #pragma unroll
            for (int r = 0; r < 4; r++)
                __builtin_nontemporal_store(acc[i][j][r] * rcp + bv,
                                            &C[(long)(row0 + r) * N + col]);
        }
    }
}

extern "C" void kernel_launch(void* const* d_in, const int* in_sizes, int n_in,
                              void* d_out, int out_size, void* d_ws, size_t ws_size,
                              hipStream_t stream) {
    const float* x = (const float*)d_in[0];    // [B,S,K] fp32
    const float* wt = (const float*)d_in[1];   // [N,K] fp32
    const float* bias = (const float*)d_in[2]; // [N] fp32
    float* out = (float*)d_out;                // [B*S, N] fp32

    const int xn = in_sizes[0];  // M*K
    const int wn = in_sizes[1];  // N*K
    const int N = in_sizes[2];
    const int K = wn / N;
    const int M = xn / K;

    unsigned char* wsb = (unsigned char*)d_ws;
    unsigned int* amax = (unsigned int*)wsb;            // 2 u32
    float* partials = (float*)(wsb + 64);               // 2*SGRID floats
    unsigned char* xq = wsb + 64 + 2 * SGRID * 4;       // M*K bytes
    unsigned char* wq = xq + (size_t)xn;                // N*K bytes

    long xn4 = (long)xn / 4, wn4 = (long)wn / 4;
    amax_partial<<<SGRID, 256, 0, stream>>>(x, xn4, wt, wn4, partials);
    quant_both<<<SGRID, 256, 0, stream>>>(x, xn4, wt, wn4, partials, amax,
                                          (unsigned int*)xq, (unsigned int*)wq);

    static bool attr_set = false;
    if (!attr_set) {
        (void)hipFuncSetAttribute((const void*)gemm_fp8mx,
                                  hipFuncAttributeMaxDynamicSharedMemorySize,
                                  131072);
        attr_set = true;
    }
    dim3 grid(N / BN, M / BM);
    gemm_fp8mx<<<grid, 512, 131072, stream>>>(xq, wq, bias, amax, out, M, N, K);
}